// Round 2
// baseline (317.202 us; speedup 1.0000x reference)
//
#include <hip/hip_runtime.h>

#define N_PTS  20000
#define TILE   256
#define SEG    8
#define QB     79                 // ceil(20000/256)
#define QPAD   (QB * 256)         // 20224
#define SEGLEN (N_PTS / SEG)      // 2500

// Reference-exact squared distance:
//   zz = ((q0*r0) + (q1*r1)) + (q2*r2)      (each op rounded f32, no fma)
//   P  = (selfQ + selfR) - 2*zz             (2*zz exact; add/sub rounded)
__device__ __forceinline__ float np_pair_dist(float sq, float sr,
                                              float qx, float qy, float qz,
                                              float rx, float ry, float rz) {
    float zz = __fadd_rn(__fadd_rn(__fmul_rn(qx, rx), __fmul_rn(qy, ry)),
                         __fmul_rn(qz, rz));
    float s  = __fadd_rn(sq, sr);
    return __fsub_rn(s, __fadd_rn(zz, zz));
}

__device__ __forceinline__ float np_self_dot(float x, float y, float z) {
    return __fadd_rn(__fadd_rn(__fmul_rn(x, x), __fmul_rn(y, y)),
                     __fmul_rn(z, z));
}

// DIRECT=false: write per-segment partial (dist, idx) into workspace.
// DIRECT=true : single segment covering [0,N), write straight to d_out.
template <bool DIRECT>
__global__ __launch_bounds__(256) void chamfer_min_kernel(
    const float* __restrict__ preds,   // [N,3]
    const float* __restrict__ gts,     // [N,3]
    float* __restrict__ pdist,         // ws partial dists (or nullptr)
    float* __restrict__ pidxf,         // ws partial idx-as-float (or nullptr)
    float* __restrict__ out)           // d_out (only used when DIRECT)
{
    __shared__ float4 spts[TILE];      // (rx, ry, rz, selfR)

    int bid = blockIdx.x;
    int dir, seg, qb;
    if (DIRECT) {
        dir = bid / QB;
        qb  = bid - dir * QB;
        seg = 0;
    } else {
        dir = bid / (QB * SEG);
        int rem = bid - dir * (QB * SEG);
        seg = rem / QB;
        qb  = rem - seg * QB;
    }
    int q = qb * 256 + threadIdx.x;

    // dir 0: queries = preds, refs = gts   -> dist1/idx1 (min over gts)
    // dir 1: queries = gts,   refs = preds -> dist2/idx2 (min over preds)
    const float* qpts = (dir == 0) ? preds : gts;
    const float* rpts = (dir == 0) ? gts   : preds;

    int qc = (q < N_PTS) ? q : (N_PTS - 1);   // clamp; write is guarded
    float qx = qpts[qc * 3 + 0];
    float qy = qpts[qc * 3 + 1];
    float qz = qpts[qc * 3 + 2];
    float sq = np_self_dot(qx, qy, qz);

    float best = 3.4e38f;
    int   bidx = 0;

    int start = DIRECT ? 0     : seg * SEGLEN;
    int end   = DIRECT ? N_PTS : (seg * SEGLEN + SEGLEN);

    for (int t = start; t < end; t += TILE) {
        int cnt = min(TILE, end - t);
        __syncthreads();
        if ((int)threadIdx.x < cnt) {
            int j = t + threadIdx.x;
            float rx = rpts[j * 3 + 0];
            float ry = rpts[j * 3 + 1];
            float rz = rpts[j * 3 + 2];
            spts[threadIdx.x] = make_float4(rx, ry, rz, np_self_dot(rx, ry, rz));
        }
        __syncthreads();

        #pragma unroll 4
        for (int k = 0; k < cnt; ++k) {
            float4 r = spts[k];
            float d = np_pair_dist(sq, r.w, qx, qy, qz, r.x, r.y, r.z);
            if (d < best) { best = d; bidx = t + k; }   // strict <: first occurrence
        }
    }

    if (q < N_PTS) {
        if (DIRECT) {
            out[dir * N_PTS + q]       = best;
            out[(2 + dir) * N_PTS + q] = (float)bidx;
        } else {
            int o = (dir * SEG + seg) * QPAD + q;
            pdist[o] = best;
            pidxf[o] = (float)bidx;
        }
    }
}

__global__ __launch_bounds__(256) void chamfer_reduce_kernel(
    const float* __restrict__ pdist,
    const float* __restrict__ pidxf,
    float* __restrict__ out)
{
    int t = blockIdx.x * 256 + threadIdx.x;
    if (t >= 2 * N_PTS) return;
    int dir = t / N_PTS;
    int q   = t - dir * N_PTS;

    float best = 3.4e38f;
    float bi   = 0.0f;
    #pragma unroll
    for (int s = 0; s < SEG; ++s) {
        int o = (dir * SEG + s) * QPAD + q;
        float d = pdist[o];
        if (d < best) { best = d; bi = pidxf[o]; }  // ascending segs: earliest index wins ties
    }
    out[dir * N_PTS + q]       = best;   // dist1 | dist2
    out[(2 + dir) * N_PTS + q] = bi;     // idx1  | idx2 (as float)
}

extern "C" void kernel_launch(void* const* d_in, const int* in_sizes, int n_in,
                              void* d_out, int out_size, void* d_ws, size_t ws_size,
                              hipStream_t stream) {
    const float* preds = (const float*)d_in[0];  // [20000, 3]
    const float* gts   = (const float*)d_in[1];  // [1, 20000, 3]
    float* out = (float*)d_out;

    size_t part_elems = (size_t)2 * SEG * QPAD;          // per array
    size_t need = 2 * part_elems * sizeof(float);        // pdist + pidxf

    if (ws_size >= need) {
        float* pdist = (float*)d_ws;
        float* pidxf = pdist + part_elems;
        dim3 grid(2 * SEG * QB);
        chamfer_min_kernel<false><<<grid, 256, 0, stream>>>(preds, gts, pdist, pidxf, out);
        dim3 rgrid((2 * N_PTS + 255) / 256);
        chamfer_reduce_kernel<<<rgrid, 256, 0, stream>>>(pdist, pidxf, out);
    } else {
        // Fallback: no workspace needed, fewer blocks (slower but correct).
        dim3 grid(2 * QB);
        chamfer_min_kernel<true><<<grid, 256, 0, stream>>>(preds, gts, nullptr, nullptr, out);
    }
}

// Round 3
// 268.198 us; speedup vs baseline: 1.1827x; 1.1827x over previous
//
#include <hip/hip_runtime.h>

#define N_PTS  20000
#define Q      8                   // queries per thread (register-blocked)
#define QPB    (256 * Q)           // 2048 queries per block
#define NQB    ((N_PTS + QPB - 1) / QPB)   // 10
#define NSEG   64                  // ref segments (parallelism)
#define SEGLEN ((N_PTS + NSEG - 1) / NSEG) // 313
#define TILE   256
#define QB79   79                  // ceil(20000/256) for fallback kernel

// ---- numpy-exact arithmetic (no FMA, no reassociation) ----
__device__ __forceinline__ float np_self_dot(float x, float y, float z) {
    return __fadd_rn(__fadd_rn(__fmul_rn(x, x), __fmul_rn(y, y)),
                     __fmul_rn(z, z));
}
// P = fl(fl(sq+sr) - fl(2*zz)), zz = fl(fl(fl(qx*rx)+fl(qy*ry))+fl(qz*rz))
__device__ __forceinline__ float np_pair(float sq, float sr,
                                         float qx, float qy, float qz,
                                         float rx, float ry, float rz) {
    float zz = __fadd_rn(__fadd_rn(__fmul_rn(qx, rx), __fmul_rn(qy, ry)),
                         __fmul_rn(qz, rz));
    return __fsub_rn(__fadd_rn(sq, sr), __fadd_rn(zz, zz));
}

// monotone float->u32 map (ascending bits == ascending float, -0 never occurs)
__device__ __forceinline__ unsigned int ordmap(float f) {
    unsigned int b = __float_as_uint(f);
    return (b & 0x80000000u) ? ~b : (b | 0x80000000u);
}

// Q=8 register-blocked min kernel; partial results combined via u64 atomicMin
// of key = (ordmap(dist) << 32) | idx.  min(key) == (min dist, then min idx)
// == numpy first-occurrence argmin, order-independent -> deterministic.
__global__ __launch_bounds__(256) void chamfer_seg_kernel(
    const float* __restrict__ preds,   // [N,3]
    const float* __restrict__ gts,     // [N,3]
    unsigned long long* __restrict__ keys)  // [2][N_PTS], pre-init 0xFF..
{
    __shared__ float4 spts[TILE];      // (rx, ry, rz, selfR)

    int bid = blockIdx.x;
    int dir = bid / (NQB * NSEG);
    int rem = bid - dir * (NQB * NSEG);
    int seg = rem / NQB;
    int qb  = rem - seg * NQB;

    // dir 0: queries = preds, refs = gts   -> dist1/idx1
    // dir 1: queries = gts,   refs = preds -> dist2/idx2
    const float* qpts = (dir == 0) ? preds : gts;
    const float* rpts = (dir == 0) ? gts   : preds;

    int qbase = qb * QPB + threadIdx.x;

    float qx[Q], qy[Q], qz[Q], sq[Q], best[Q];
    int   bidx[Q];
    #pragma unroll
    for (int i = 0; i < Q; ++i) {
        int q  = qbase + i * 256;
        int qc = (q < N_PTS) ? q : (N_PTS - 1);   // clamp; atomic is guarded
        qx[i] = qpts[qc * 3 + 0];
        qy[i] = qpts[qc * 3 + 1];
        qz[i] = qpts[qc * 3 + 2];
        sq[i] = np_self_dot(qx[i], qy[i], qz[i]);
        best[i] = 3.4e38f;
        bidx[i] = 0;
    }

    int s0 = seg * SEGLEN;
    int s1 = min(s0 + SEGLEN, N_PTS);

    for (int t = s0; t < s1; t += TILE) {
        int cnt = min(TILE, s1 - t);
        __syncthreads();
        if ((int)threadIdx.x < cnt) {
            int j = t + threadIdx.x;
            float rx = rpts[j * 3 + 0];
            float ry = rpts[j * 3 + 1];
            float rz = rpts[j * 3 + 2];
            spts[threadIdx.x] = make_float4(rx, ry, rz, np_self_dot(rx, ry, rz));
        }
        __syncthreads();

        #pragma unroll 2
        for (int k = 0; k < cnt; ++k) {
            float4 r = spts[k];             // 1 ds_read_b128 amortized over Q pairs
            #pragma unroll
            for (int i = 0; i < Q; ++i) {
                float d = np_pair(sq[i], r.w, qx[i], qy[i], qz[i], r.x, r.y, r.z);
                if (d < best[i]) { best[i] = d; bidx[i] = t + k; }  // strict <
            }
        }
    }

    #pragma unroll
    for (int i = 0; i < Q; ++i) {
        int q = qbase + i * 256;
        if (q < N_PTS) {
            unsigned long long key =
                ((unsigned long long)ordmap(best[i]) << 32) | (unsigned int)bidx[i];
            atomicMin(&keys[dir * N_PTS + q], key);
        }
    }
}

__global__ __launch_bounds__(256) void chamfer_finalize(
    const unsigned long long* __restrict__ keys,
    float* __restrict__ out)
{
    int t = blockIdx.x * 256 + threadIdx.x;
    if (t >= 2 * N_PTS) return;
    int dir = t / N_PTS;
    int q   = t - dir * N_PTS;
    unsigned long long key = keys[dir * N_PTS + q];
    unsigned int hi = (unsigned int)(key >> 32);
    unsigned int lo = (unsigned int)(key & 0xFFFFFFFFu);
    unsigned int b  = (hi & 0x80000000u) ? (hi ^ 0x80000000u) : ~hi;  // inverse ordmap
    out[dir * N_PTS + q]       = __uint_as_float(b);   // dist1 | dist2
    out[(2 + dir) * N_PTS + q] = (float)lo;            // idx1  | idx2 (as float)
}

// ---- fallback (no workspace): round-2 direct kernel, correct but slow ----
__global__ __launch_bounds__(256) void chamfer_direct_kernel(
    const float* __restrict__ preds,
    const float* __restrict__ gts,
    float* __restrict__ out)
{
    __shared__ float4 spts[TILE];
    int bid = blockIdx.x;
    int dir = bid / QB79;
    int qb  = bid - dir * QB79;
    int q   = qb * 256 + threadIdx.x;

    const float* qpts = (dir == 0) ? preds : gts;
    const float* rpts = (dir == 0) ? gts   : preds;

    int qc = (q < N_PTS) ? q : (N_PTS - 1);
    float qx = qpts[qc * 3 + 0], qy = qpts[qc * 3 + 1], qz = qpts[qc * 3 + 2];
    float sq = np_self_dot(qx, qy, qz);
    float best = 3.4e38f;
    int   bidx = 0;

    for (int t = 0; t < N_PTS; t += TILE) {
        int cnt = min(TILE, N_PTS - t);
        __syncthreads();
        if ((int)threadIdx.x < cnt) {
            int j = t + threadIdx.x;
            float rx = rpts[j * 3 + 0], ry = rpts[j * 3 + 1], rz = rpts[j * 3 + 2];
            spts[threadIdx.x] = make_float4(rx, ry, rz, np_self_dot(rx, ry, rz));
        }
        __syncthreads();
        #pragma unroll 4
        for (int k = 0; k < cnt; ++k) {
            float4 r = spts[k];
            float d = np_pair(sq, r.w, qx, qy, qz, r.x, r.y, r.z);
            if (d < best) { best = d; bidx = t + k; }
        }
    }
    if (q < N_PTS) {
        out[dir * N_PTS + q]       = best;
        out[(2 + dir) * N_PTS + q] = (float)bidx;
    }
}

extern "C" void kernel_launch(void* const* d_in, const int* in_sizes, int n_in,
                              void* d_out, int out_size, void* d_ws, size_t ws_size,
                              hipStream_t stream) {
    const float* preds = (const float*)d_in[0];  // [20000, 3]
    const float* gts   = (const float*)d_in[1];  // [1, 20000, 3]
    float* out = (float*)d_out;

    size_t need = (size_t)2 * N_PTS * sizeof(unsigned long long);  // 320 KB

    if (ws_size >= need) {
        unsigned long long* keys = (unsigned long long*)d_ws;
        hipMemsetAsync(d_ws, 0xFF, need, stream);   // keys = ULLONG_MAX
        dim3 grid(2 * NQB * NSEG);                  // 1280 blocks
        chamfer_seg_kernel<<<grid, 256, 0, stream>>>(preds, gts, keys);
        chamfer_finalize<<<(2 * N_PTS + 255) / 256, 256, 0, stream>>>(keys, out);
    } else {
        chamfer_direct_kernel<<<2 * QB79, 256, 0, stream>>>(preds, gts, out);
    }
}

// Round 4
// 192.891 us; speedup vs baseline: 1.6445x; 1.3904x over previous
//
#include <hip/hip_runtime.h>

#define N_PTS  20000
#define Q      8                    // queries per thread (named-scalar unrolled)
#define QPB    (256 * Q)            // 2048 queries per block
#define NQB    ((N_PTS + QPB - 1) / QPB)   // 10
#define SEGLEN 400                  // ref points per segment (= LDS tile)
#define NSEG   (N_PTS / SEGLEN)     // 50, exact
#define QB79   79                   // for fallback kernel

// ---- numpy-exact arithmetic (no FMA, no reassociation) ----
__device__ __forceinline__ float np_self_dot(float x, float y, float z) {
    return __fadd_rn(__fadd_rn(__fmul_rn(x, x), __fmul_rn(y, y)),
                     __fmul_rn(z, z));
}

// monotone float->u32 map (ascending bits == ascending float)
__device__ __forceinline__ unsigned int ordmap(float f) {
    unsigned int b = __float_as_uint(f);
    return (b & 0x80000000u) ? ~b : (b | 0x80000000u);
}

// Per-segment min kernel. Refs staged in LDS pre-doubled: (2rx,2ry,2rz,sr).
// d = fl( fl(sq+sr) - fl(qx*2rx + qy*2ry + qz*2rz) )  ==  fl(fl(sq+sr)-fl(2*zz))
// bit-exact vs numpy (x2 commutes with round-to-nearest away from denormals).
// Partials combined via u64 atomicMin of key = (ordmap(d)<<32 | idx):
// min key == (min dist, then min idx) == numpy first-occurrence argmin.
__global__ __launch_bounds__(256, 4) void chamfer_seg_kernel(
    const float* __restrict__ preds,        // [N,3]
    const float* __restrict__ gts,          // [N,3]
    unsigned long long* __restrict__ keys)  // [2][N_PTS], pre-init 0xFF..
{
    __shared__ float4 spts[SEGLEN];

    int bid = blockIdx.x;
    int dir = bid / (NQB * NSEG);
    int rem = bid - dir * (NQB * NSEG);
    int seg = rem / NQB;
    int qb  = rem - seg * NQB;

    // dir 0: queries = preds, refs = gts   -> dist1/idx1
    // dir 1: queries = gts,   refs = preds -> dist2/idx2
    const float* qpts = (dir == 0) ? preds : gts;
    const float* rpts = (dir == 0) ? gts   : preds;

    int qbase = qb * QPB + threadIdx.x;

    // ---- load Q=8 queries into named scalars (no arrays -> nothing to split)
#define LOADQ(n)                                                         \
    float qx##n, qy##n, qz##n, sq##n, best##n; int bidx##n;              \
    {   int q  = qbase + n * 256;                                        \
        int qc = (q < N_PTS) ? q : (N_PTS - 1);                          \
        qx##n = qpts[qc * 3 + 0];                                        \
        qy##n = qpts[qc * 3 + 1];                                        \
        qz##n = qpts[qc * 3 + 2];                                        \
        sq##n = np_self_dot(qx##n, qy##n, qz##n);                        \
        best##n = 3.4e38f; bidx##n = 0; }
    LOADQ(0) LOADQ(1) LOADQ(2) LOADQ(3) LOADQ(4) LOADQ(5) LOADQ(6) LOADQ(7)
#undef LOADQ

    // ---- stage segment refs into LDS, pre-doubled
    int s0 = seg * SEGLEN;
    for (int j = threadIdx.x; j < SEGLEN; j += 256) {
        int g = s0 + j;
        float rx = rpts[g * 3 + 0];
        float ry = rpts[g * 3 + 1];
        float rz = rpts[g * 3 + 2];
        spts[j] = make_float4(rx + rx, ry + ry, rz + rz,
                              np_self_dot(rx, ry, rz));
    }
    __syncthreads();

    // ---- main loop: one ds_read_b128 per k, amortized over 8 chains
#define CHAIN(n)                                                          \
    {   float d = __fsub_rn(__fadd_rn(sq##n, rw),                         \
            __fadd_rn(__fadd_rn(__fmul_rn(qx##n, rx), __fmul_rn(qy##n, ry)), \
                      __fmul_rn(qz##n, rz)));                             \
        bool lt = d < best##n;                                            \
        best##n = lt ? d : best##n;                                       \
        bidx##n = lt ? kk : bidx##n; }

    #pragma unroll 2
    for (int k = 0; k < SEGLEN; ++k) {
        float4 r = spts[k];
        float rx = r.x, ry = r.y, rz = r.z, rw = r.w;
        int   kk = s0 + k;
        CHAIN(0) CHAIN(1) CHAIN(2) CHAIN(3)
        CHAIN(4) CHAIN(5) CHAIN(6) CHAIN(7)
    }
#undef CHAIN

    // ---- fold partials into global keys
#define EMIT(n)                                                           \
    {   int q = qbase + n * 256;                                          \
        if (q < N_PTS) {                                                  \
            unsigned long long key =                                      \
                ((unsigned long long)ordmap(best##n) << 32) |             \
                (unsigned int)bidx##n;                                    \
            atomicMin(&keys[dir * N_PTS + q], key);                       \
        } }
    EMIT(0) EMIT(1) EMIT(2) EMIT(3) EMIT(4) EMIT(5) EMIT(6) EMIT(7)
#undef EMIT
}

__global__ __launch_bounds__(256) void chamfer_finalize(
    const unsigned long long* __restrict__ keys,
    float* __restrict__ out)
{
    int t = blockIdx.x * 256 + threadIdx.x;
    if (t >= 2 * N_PTS) return;
    int dir = t / N_PTS;
    int q   = t - dir * N_PTS;
    unsigned long long key = keys[dir * N_PTS + q];
    unsigned int hi = (unsigned int)(key >> 32);
    unsigned int lo = (unsigned int)(key & 0xFFFFFFFFu);
    unsigned int b  = (hi & 0x80000000u) ? (hi ^ 0x80000000u) : ~hi;  // inverse ordmap
    out[dir * N_PTS + q]       = __uint_as_float(b);   // dist1 | dist2
    out[(2 + dir) * N_PTS + q] = (float)lo;            // idx1  | idx2 (as float)
}

// ---- fallback (no workspace): direct kernel, correct but slow ----
__device__ __forceinline__ float np_pair(float sq, float sr,
                                         float qx, float qy, float qz,
                                         float rx, float ry, float rz) {
    float zz = __fadd_rn(__fadd_rn(__fmul_rn(qx, rx), __fmul_rn(qy, ry)),
                         __fmul_rn(qz, rz));
    return __fsub_rn(__fadd_rn(sq, sr), __fadd_rn(zz, zz));
}

__global__ __launch_bounds__(256) void chamfer_direct_kernel(
    const float* __restrict__ preds,
    const float* __restrict__ gts,
    float* __restrict__ out)
{
    __shared__ float4 spts[256];
    int bid = blockIdx.x;
    int dir = bid / QB79;
    int qb  = bid - dir * QB79;
    int q   = qb * 256 + threadIdx.x;

    const float* qpts = (dir == 0) ? preds : gts;
    const float* rpts = (dir == 0) ? gts   : preds;

    int qc = (q < N_PTS) ? q : (N_PTS - 1);
    float qx = qpts[qc * 3 + 0], qy = qpts[qc * 3 + 1], qz = qpts[qc * 3 + 2];
    float sq = np_self_dot(qx, qy, qz);
    float best = 3.4e38f;
    int   bidx = 0;

    for (int t = 0; t < N_PTS; t += 256) {
        int cnt = min(256, N_PTS - t);
        __syncthreads();
        if ((int)threadIdx.x < cnt) {
            int j = t + threadIdx.x;
            float rx = rpts[j * 3 + 0], ry = rpts[j * 3 + 1], rz = rpts[j * 3 + 2];
            spts[threadIdx.x] = make_float4(rx, ry, rz, np_self_dot(rx, ry, rz));
        }
        __syncthreads();
        for (int k = 0; k < cnt; ++k) {
            float4 r = spts[k];
            float d = np_pair(sq, r.w, qx, qy, qz, r.x, r.y, r.z);
            if (d < best) { best = d; bidx = t + k; }
        }
    }
    if (q < N_PTS) {
        out[dir * N_PTS + q]       = best;
        out[(2 + dir) * N_PTS + q] = (float)bidx;
    }
}

extern "C" void kernel_launch(void* const* d_in, const int* in_sizes, int n_in,
                              void* d_out, int out_size, void* d_ws, size_t ws_size,
                              hipStream_t stream) {
    const float* preds = (const float*)d_in[0];  // [20000, 3]
    const float* gts   = (const float*)d_in[1];  // [1, 20000, 3]
    float* out = (float*)d_out;

    size_t need = (size_t)2 * N_PTS * sizeof(unsigned long long);  // 320 KB

    if (ws_size >= need) {
        unsigned long long* keys = (unsigned long long*)d_ws;
        hipMemsetAsync(d_ws, 0xFF, need, stream);   // keys = ULLONG_MAX
        dim3 grid(2 * NQB * NSEG);                  // 1000 blocks
        chamfer_seg_kernel<<<grid, 256, 0, stream>>>(preds, gts, keys);
        chamfer_finalize<<<(2 * N_PTS + 255) / 256, 256, 0, stream>>>(keys, out);
    } else {
        chamfer_direct_kernel<<<2 * QB79, 256, 0, stream>>>(preds, gts, out);
    }
}